// Round 1
// baseline (925.889 us; speedup 1.0000x reference)
//
#include <hip/hip_runtime.h>
#include <hip/hip_bf16.h>

#define B_   4
#define LQ_  1024
#define LK_  1024
#define LKL_ 512
#define DX_  1024
#define H_   16
#define DK_  64
#define HDK_ 1024
#define NEG_ -1e9f
#define EPS_ 1e-5f

typedef __bf16 bf16_t;
typedef __bf16 bf16x8 __attribute__((ext_vector_type(8)));
typedef float  f32x4  __attribute__((ext_vector_type(4)));

__device__ inline f32x4 mfma16(bf16x8 a, bf16x8 b, f32x4 c) {
    return __builtin_amdgcn_mfma_f32_16x16x32_bf16(a, b, c, 0, 0, 0);
}

__device__ inline float waveMax(float v) {
#pragma unroll
    for (int o = 32; o > 0; o >>= 1) v = fmaxf(v, __shfl_xor(v, o, 64));
    return v;
}
__device__ inline float waveSum(float v) {
#pragma unroll
    for (int o = 32; o > 0; o >>= 1) v += __shfl_xor(v, o, 64);
    return v;
}

// ---------------------------------------------------------------------------
// Detect how the bool masks were materialized on device: int32 (flag 0),
// uint8 (flag 1), or float32 (flag 2). Deterministic given fixed inputs.
// ---------------------------------------------------------------------------
__global__ void detect_mask_kernel(const unsigned* __restrict__ m, unsigned* __restrict__ flag)
{
    __shared__ unsigned w[256];
    w[threadIdx.x] = m[threadIdx.x];
    __syncthreads();
    if (threadIdx.x == 0) {
        bool all01 = true, allf = true;
        for (int i = 0; i < 256; ++i) {
            unsigned v = w[i];
            all01 = all01 && (v <= 1u);
            allf  = allf  && (v == 0u || v == 0x3F800000u);
        }
        *flag = all01 ? 0u : (allf ? 2u : 1u);
    }
}

// ---------------------------------------------------------------------------
// Generic bf16-MFMA GEMM: C = A(f32, MxK) * W(f32, KxN) + bias.
// HEADOUT: write bf16 to (B,H,L,DK) head layout.   else: f32 row-major + resid.
// 128x128 tile, BK=32, 4 waves (2x2), 16x16x32 MFMA.
// ---------------------------------------------------------------------------
template<bool HEADOUT>
__global__ __launch_bounds__(256) void gemm_bf16_kernel(
    const float* __restrict__ A, const float* __restrict__ W,
    const float* __restrict__ bias,
    bf16_t* __restrict__ outH, float* __restrict__ outF,
    const float* __restrict__ resid,
    int M, int N, int K, int lshift)
{
    __shared__ bf16_t As[128][40];   // stride 40 bf16 = 80B: 16B-aligned rows, 2-way banks (free)
    __shared__ bf16_t Bs[128][40];   // Bs[n][k] (W tile transposed)
    const int tid  = threadIdx.x;
    const int wave = tid >> 6, lane = tid & 63;
    const int bm0 = blockIdx.y * 128, bn0 = blockIdx.x * 128;
    const int wr = (wave >> 1) * 64, wc = (wave & 1) * 64;
    const int lr = lane & 15, lk8 = (lane >> 4) * 8;

    f32x4 acc[4][4] = {};

    const int fA = (tid & 7) * 4;    // k-chunk within A tile
    const int rA = tid >> 3;         // 0..31
    const int fB = (tid & 31) * 4;   // n-chunk within B tile
    const int kB = tid >> 5;         // 0..7

    for (int k0 = 0; k0 < K; k0 += 32) {
        __syncthreads();
#pragma unroll
        for (int rr = 0; rr < 4; ++rr) {
            const int r = rA + rr * 32;
            const float4 v = *(const float4*)&A[(size_t)(bm0 + r) * K + k0 + fA];
            As[r][fA + 0] = (bf16_t)v.x;
            As[r][fA + 1] = (bf16_t)v.y;
            As[r][fA + 2] = (bf16_t)v.z;
            As[r][fA + 3] = (bf16_t)v.w;
        }
#pragma unroll
        for (int kk = 0; kk < 4; ++kk) {
            const int kx = kB + kk * 8;
            const float4 v = *(const float4*)&W[(size_t)(k0 + kx) * N + bn0 + fB];
            Bs[fB + 0][kx] = (bf16_t)v.x;
            Bs[fB + 1][kx] = (bf16_t)v.y;
            Bs[fB + 2][kx] = (bf16_t)v.z;
            Bs[fB + 3][kx] = (bf16_t)v.w;
        }
        __syncthreads();
        bf16x8 af[4], bfr[4];
#pragma unroll
        for (int i = 0; i < 4; ++i) {
            af[i]  = *(const bf16x8*)&As[wr + i * 16 + lr][lk8];
            bfr[i] = *(const bf16x8*)&Bs[wc + i * 16 + lr][lk8];
        }
#pragma unroll
        for (int mi = 0; mi < 4; ++mi)
#pragma unroll
            for (int ni = 0; ni < 4; ++ni)
                acc[mi][ni] = mfma16(af[mi], bfr[ni], acc[mi][ni]);
    }

#pragma unroll
    for (int mi = 0; mi < 4; ++mi) {
#pragma unroll
        for (int ni = 0; ni < 4; ++ni) {
#pragma unroll
            for (int r = 0; r < 4; ++r) {
                const int row = bm0 + wr + mi * 16 + (lane >> 4) * 4 + r;
                const int col = bn0 + wc + ni * 16 + (lane & 15);
                const float val = acc[mi][ni][r] + bias[col];
                if (HEADOUT) {
                    const int b = row >> lshift, l = row & ((1 << lshift) - 1);
                    const int h = col >> 6, d = col & 63;
                    outH[(((size_t)(b * H_ + h) << lshift) + l) * DK_ + d] = (bf16_t)val;
                } else {
                    const size_t idx = (size_t)row * N + col;
                    outF[idx] = val + resid[idx];
                }
            }
        }
    }
}

// ---------------------------------------------------------------------------
// Scores: S[bh][q][k] = mask ? -1e9 : (Qh . Kh)/8.   64x64 tile per block.
// ---------------------------------------------------------------------------
__global__ __launch_bounds__(256) void scores_kernel(
    const bf16_t* __restrict__ Qh, const bf16_t* __restrict__ Kh,
    const void* __restrict__ mask, const unsigned* __restrict__ flagp,
    float* __restrict__ S, const int LKx)
{
    const int bh = blockIdx.z, b = bh >> 4;
    const int q0 = blockIdx.y * 64, k0 = blockIdx.x * 64;
    const int wave = threadIdx.x >> 6, lane = threadIdx.x & 63;
    const int lr = lane & 15, lk8 = (lane >> 4) * 8;
    const bf16_t* Qb = Qh + (size_t)bh * LQ_ * DK_;
    const bf16_t* Kb = Kh + (size_t)bh * LKx * DK_;
    f32x4 acc[4] = {};
    const int qrow = q0 + wave * 16 + lr;
#pragma unroll
    for (int ks = 0; ks < 2; ++ks) {
        const bf16x8 a = *(const bf16x8*)&Qb[(size_t)qrow * DK_ + ks * 32 + lk8];
#pragma unroll
        for (int ni = 0; ni < 4; ++ni) {
            const bf16x8 bb = *(const bf16x8*)&Kb[(size_t)(k0 + ni * 16 + lr) * DK_ + ks * 32 + lk8];
            acc[ni] = mfma16(a, bb, acc[ni]);
        }
    }
    const unsigned flag = *flagp;
#pragma unroll
    for (int ni = 0; ni < 4; ++ni) {
#pragma unroll
        for (int r = 0; r < 4; ++r) {
            const int row = q0 + wave * 16 + (lane >> 4) * 4 + r;
            const int col = k0 + ni * 16 + (lane & 15);
            const size_t midx = ((size_t)b * LQ_ + row) * LKx + col;
            const bool msk = (flag == 0u) ? (((const int*)mask)[midx] != 0)
                           : (flag == 2u) ? (((const float*)mask)[midx] != 0.0f)
                                          : (((const unsigned char*)mask)[midx] != 0);
            S[((size_t)bh * LQ_ + row) * LKx + col] = msk ? NEG_ : acc[ni][r] * 0.125f;
        }
    }
}

// ---------------------------------------------------------------------------
// Row softmax in place. One block per row.
// ---------------------------------------------------------------------------
template<int LKX>
__global__ __launch_bounds__(256) void softmax_kernel(float* __restrict__ S)
{
    __shared__ float redm[4], reds[4];
    const int tid = threadIdx.x, wave = tid >> 6, lane = tid & 63;
    float* p = S + (size_t)blockIdx.x * LKX;
    constexpr int NV = LKX / 256;
    float v[NV];
    float m = -INFINITY;
#pragma unroll
    for (int i = 0; i < NV; ++i) { v[i] = p[tid + i * 256]; m = fmaxf(m, v[i]); }
    m = waveMax(m);
    if (lane == 0) redm[wave] = m;
    __syncthreads();
    m = fmaxf(fmaxf(redm[0], redm[1]), fmaxf(redm[2], redm[3]));
    float s = 0.f;
#pragma unroll
    for (int i = 0; i < NV; ++i) { v[i] = __expf(v[i] - m); s += v[i]; }
    s = waveSum(s);
    if (lane == 0) reds[wave] = s;
    __syncthreads();
    s = reds[0] + reds[1] + reds[2] + reds[3];
    const float inv = 1.f / s;
#pragma unroll
    for (int i = 0; i < NV; ++i) p[tid + i * 256] = v[i] * inv;
}

// ---------------------------------------------------------------------------
// PV: comb[b][q][h*64+d] = 0.5*(Pc@Vh + Pl@Vlh)   (ALPHA = 0.5 exactly)
// 64 q-rows x 64 d per block; 4 waves, 1x4 fragments each.
// ---------------------------------------------------------------------------
__global__ __launch_bounds__(256) void pv_kernel(
    const float* __restrict__ Pc, const float* __restrict__ Pl,
    const bf16_t* __restrict__ Vh, const bf16_t* __restrict__ Vlh,
    float* __restrict__ comb)
{
    __shared__ bf16_t Ps[64][40];
    __shared__ bf16_t Vs[64][40];   // Vs[d][k]
    const int bh = blockIdx.y, b = bh >> 4, h = bh & 15;
    const int q0 = blockIdx.x * 64;
    const int tid = threadIdx.x, wave = tid >> 6, lane = tid & 63;
    const int lr = lane & 15, lk8 = (lane >> 4) * 8;
    const int fA = (tid & 7) * 4, rA = tid >> 3;   // P staging
    const int cV = (tid & 7) * 8, kV = tid >> 3;   // V staging (transpose)
    f32x4 acc[4] = {};
#pragma unroll
    for (int phase = 0; phase < 2; ++phase) {
        const float*  P   = phase ? Pl  : Pc;
        const bf16_t* V   = phase ? Vlh : Vh;
        const int     LKx = phase ? LKL_ : LK_;
        const float*  Pb  = P + ((size_t)bh * LQ_ + q0) * LKx;
        const bf16_t* Vb  = V + (size_t)bh * LKx * DK_;
        for (int k0 = 0; k0 < LKx; k0 += 32) {
            __syncthreads();
#pragma unroll
            for (int rr = 0; rr < 2; ++rr) {
                const int r = rA + rr * 32;
                const float4 v = *(const float4*)&Pb[(size_t)r * LKx + k0 + fA];
                Ps[r][fA + 0] = (bf16_t)v.x;
                Ps[r][fA + 1] = (bf16_t)v.y;
                Ps[r][fA + 2] = (bf16_t)v.z;
                Ps[r][fA + 3] = (bf16_t)v.w;
            }
            {
                const bf16x8 vv = *(const bf16x8*)&Vb[(size_t)(k0 + kV) * DK_ + cV];
#pragma unroll
                for (int j = 0; j < 8; ++j) Vs[cV + j][kV] = vv[j];
            }
            __syncthreads();
            const bf16x8 a = *(const bf16x8*)&Ps[wave * 16 + lr][lk8];
#pragma unroll
            for (int ni = 0; ni < 4; ++ni) {
                const bf16x8 bb = *(const bf16x8*)&Vs[ni * 16 + lr][lk8];
                acc[ni] = mfma16(a, bb, acc[ni]);
            }
        }
    }
#pragma unroll
    for (int ni = 0; ni < 4; ++ni) {
#pragma unroll
        for (int r = 0; r < 4; ++r) {
            const int row = q0 + wave * 16 + (lane >> 4) * 4 + r;
            const int d = ni * 16 + (lane & 15);
            comb[((size_t)b * LQ_ + row) * HDK_ + h * DK_ + d] = 0.5f * acc[ni][r];
        }
    }
}

// ---------------------------------------------------------------------------
// LayerNorm over last dim (1024). One block per row.
// ---------------------------------------------------------------------------
__global__ __launch_bounds__(256) void ln_kernel(
    const float* __restrict__ Y, const float* __restrict__ g,
    const float* __restrict__ be, float* __restrict__ out)
{
    __shared__ float red1[4], red2[4];
    const int tid = threadIdx.x, wave = tid >> 6, lane = tid & 63;
    const float* p = Y + (size_t)blockIdx.x * DX_;
    const float4 x = *(const float4*)&p[tid * 4];
    float s  = x.x + x.y + x.z + x.w;
    float ss = x.x * x.x + x.y * x.y + x.z * x.z + x.w * x.w;
    s = waveSum(s); ss = waveSum(ss);
    if (lane == 0) { red1[wave] = s; red2[wave] = ss; }
    __syncthreads();
    s  = red1[0] + red1[1] + red1[2] + red1[3];
    ss = red2[0] + red2[1] + red2[2] + red2[3];
    const float mean = s * (1.f / DX_);
    const float var  = ss * (1.f / DX_) - mean * mean;
    const float rstd = rsqrtf(var + EPS_);
    const float4 gg = *(const float4*)&g[tid * 4];
    const float4 bb = *(const float4*)&be[tid * 4];
    float4 o;
    o.x = (x.x - mean) * rstd * gg.x + bb.x;
    o.y = (x.y - mean) * rstd * gg.y + bb.y;
    o.z = (x.z - mean) * rstd * gg.z + bb.z;
    o.w = (x.w - mean) * rstd * gg.w + bb.w;
    *(float4*)&out[(size_t)blockIdx.x * DX_ + tid * 4] = o;
}

// ---------------------------------------------------------------------------
extern "C" void kernel_launch(void* const* d_in, const int* in_sizes, int n_in,
                              void* d_out, int out_size, void* d_ws, size_t ws_size,
                              hipStream_t stream)
{
    const float* q    = (const float*)d_in[0];
    const float* k    = (const float*)d_in[1];
    const float* v    = (const float*)d_in[2];
    const float* kl   = (const float*)d_in[3];
    const float* vl   = (const float*)d_in[4];
    const void*  mask  = d_in[5];
    const void*  maskl = d_in[6];
    const float* wq_w  = (const float*)d_in[7];
    const float* wq_b  = (const float*)d_in[8];
    const float* wk_w  = (const float*)d_in[9];
    const float* wk_b  = (const float*)d_in[10];
    const float* wv_w  = (const float*)d_in[11];
    const float* wv_b  = (const float*)d_in[12];
    const float* wkl_w = (const float*)d_in[13];
    const float* wkl_b = (const float*)d_in[14];
    const float* wvl_w = (const float*)d_in[15];
    const float* wvl_b = (const float*)d_in[16];
    const float* wo_w  = (const float*)d_in[17];
    const float* wo_b  = (const float*)d_in[18];
    const float* ln_g  = (const float*)d_in[19];
    const float* ln_b  = (const float*)d_in[20];

    char* ws = (char*)d_ws;
    bf16_t* qh   = (bf16_t*)(ws);
    bf16_t* kh   = (bf16_t*)(ws + (size_t)( 8u << 20));
    bf16_t* vh   = (bf16_t*)(ws + (size_t)(16u << 20));
    bf16_t* klh  = (bf16_t*)(ws + (size_t)(24u << 20));
    bf16_t* vlh  = (bf16_t*)(ws + (size_t)(28u << 20));
    float*  comb = (float*) (ws + (size_t)(32u << 20));
    float*  ypre = (float*) (ws + (size_t)(48u << 20));
    unsigned* flag = (unsigned*)(ws + (size_t)(64u << 20));

    float* y_out = (float*)d_out;
    float* Sc = y_out + (size_t)B_ * LQ_ * DX_;
    float* Sl = Sc + (size_t)B_ * H_ * LQ_ * LK_;

    detect_mask_kernel<<<dim3(1), dim3(256), 0, stream>>>((const unsigned*)mask, flag);

    // Projections -> bf16 head tensors (B,H,L,DK)
    gemm_bf16_kernel<true><<<dim3(8, 32), 256, 0, stream>>>(q,  wq_w,  wq_b,  qh,  nullptr, nullptr, 4096, 1024, 1024, 10);
    gemm_bf16_kernel<true><<<dim3(8, 32), 256, 0, stream>>>(k,  wk_w,  wk_b,  kh,  nullptr, nullptr, 4096, 1024, 1024, 10);
    gemm_bf16_kernel<true><<<dim3(8, 32), 256, 0, stream>>>(v,  wv_w,  wv_b,  vh,  nullptr, nullptr, 4096, 1024, 1024, 10);
    gemm_bf16_kernel<true><<<dim3(8, 16), 256, 0, stream>>>(kl, wkl_w, wkl_b, klh, nullptr, nullptr, 2048, 1024, 1024,  9);
    gemm_bf16_kernel<true><<<dim3(8, 16), 256, 0, stream>>>(vl, wvl_w, wvl_b, vlh, nullptr, nullptr, 2048, 1024, 1024,  9);

    // Masked scaled scores into the attn output regions
    scores_kernel<<<dim3(16, 16, 64), 256, 0, stream>>>(qh, kh,  mask,  flag, Sc, LK_);
    scores_kernel<<<dim3( 8, 16, 64), 256, 0, stream>>>(qh, klh, maskl, flag, Sl, LKL_);

    // Softmax in place (these ARE the attn_c / attn_l outputs)
    softmax_kernel<LK_ ><<<B_ * H_ * LQ_, 256, 0, stream>>>(Sc);
    softmax_kernel<LKL_><<<B_ * H_ * LQ_, 256, 0, stream>>>(Sl);

    // PV + 0.5/0.5 combine -> comb (B,LQ,H*DK) f32
    pv_kernel<<<dim3(16, 64), 256, 0, stream>>>(Sc, Sl, vh, vlh, comb);

    // Output projection + bias + residual(q) -> ypre
    gemm_bf16_kernel<false><<<dim3(8, 32), 256, 0, stream>>>(comb, wo_w, wo_b, nullptr, ypre, q, 4096, 1024, 1024, 0);

    // LayerNorm -> y
    ln_kernel<<<4096, 256, 0, stream>>>(ypre, ln_g, ln_b, y_out);
}

// Round 2
// 640.406 us; speedup vs baseline: 1.4458x; 1.4458x over previous
//
#include <hip/hip_runtime.h>
#include <hip/hip_bf16.h>

#define B_   4
#define LQ_  1024
#define LK_  1024
#define LKL_ 512
#define DX_  1024
#define H_   16
#define DK_  64
#define HDK_ 1024
#define NEG_ -1e9f
#define EPS_ 1e-5f

typedef __bf16 bf16_t;
typedef __bf16 bf16x8 __attribute__((ext_vector_type(8)));
typedef __bf16 bf16x4 __attribute__((ext_vector_type(4)));
typedef float  f32x4  __attribute__((ext_vector_type(4)));

__device__ inline f32x4 mfma16(bf16x8 a, bf16x8 b, f32x4 c) {
    return __builtin_amdgcn_mfma_f32_16x16x32_bf16(a, b, c, 0, 0, 0);
}

__device__ inline float waveMax(float v) {
#pragma unroll
    for (int o = 32; o > 0; o >>= 1) v = fmaxf(v, __shfl_xor(v, o, 64));
    return v;
}
__device__ inline float waveSum(float v) {
#pragma unroll
    for (int o = 32; o > 0; o >>= 1) v += __shfl_xor(v, o, 64);
    return v;
}

// Swizzled index into the 32x1024 bf16 score tile: XOR row bits into the
// 16B-slot bits so column-slice reads (PV A-frags, stride 2048B rows) hit
// 32 distinct banks instead of a 16-way conflict.
__device__ inline int sidx(int row, int col) {
    return (row * 1024 + col) ^ ((row & 15) << 3);
}

// ---------------------------------------------------------------------------
// Detect mask materialization: int32 (0), uint8 (1), float32 (2).
// ---------------------------------------------------------------------------
__global__ void detect_mask_kernel(const unsigned* __restrict__ m, unsigned* __restrict__ flag)
{
    __shared__ unsigned w[256];
    w[threadIdx.x] = m[threadIdx.x];
    __syncthreads();
    if (threadIdx.x == 0) {
        bool all01 = true, allf = true;
        for (int i = 0; i < 256; ++i) {
            unsigned v = w[i];
            all01 = all01 && (v <= 1u);
            allf  = allf  && (v == 0u || v == 0x3F800000u);
        }
        *flag = all01 ? 0u : (allf ? 2u : 1u);
    }
}

// ---------------------------------------------------------------------------
// Projection GEMM: C = A(f32,MxK) * W(f32,KxN) + bias.
// HEADOUT: bf16 (B,H,L,DK).  else: f32 + residual.
// ---------------------------------------------------------------------------
template<bool HEADOUT>
__global__ __launch_bounds__(256) void gemm_bf16_kernel(
    const float* __restrict__ A, const float* __restrict__ W,
    const float* __restrict__ bias,
    bf16_t* __restrict__ outH, float* __restrict__ outF,
    const float* __restrict__ resid,
    int M, int N, int K, int lshift)
{
    __shared__ bf16_t As[128][40];
    __shared__ bf16_t Bs[128][40];
    const int tid  = threadIdx.x;
    const int wave = tid >> 6, lane = tid & 63;
    const int bm0 = blockIdx.y * 128, bn0 = blockIdx.x * 128;
    const int wr = (wave >> 1) * 64, wc = (wave & 1) * 64;
    const int lr = lane & 15, lk8 = (lane >> 4) * 8;

    f32x4 acc[4][4] = {};

    const int fA = (tid & 7) * 4;
    const int rA = tid >> 3;
    const int fB = (tid & 31) * 4;
    const int kB = tid >> 5;

    for (int k0 = 0; k0 < K; k0 += 32) {
        __syncthreads();
#pragma unroll
        for (int rr = 0; rr < 4; ++rr) {
            const int r = rA + rr * 32;
            const float4 v = *(const float4*)&A[(size_t)(bm0 + r) * K + k0 + fA];
            bf16x4 t;
            t[0] = (bf16_t)v.x; t[1] = (bf16_t)v.y; t[2] = (bf16_t)v.z; t[3] = (bf16_t)v.w;
            *(bf16x4*)&As[r][fA] = t;
        }
#pragma unroll
        for (int kk = 0; kk < 4; ++kk) {
            const int kx = kB + kk * 8;
            const float4 v = *(const float4*)&W[(size_t)(k0 + kx) * N + bn0 + fB];
            Bs[fB + 0][kx] = (bf16_t)v.x;
            Bs[fB + 1][kx] = (bf16_t)v.y;
            Bs[fB + 2][kx] = (bf16_t)v.z;
            Bs[fB + 3][kx] = (bf16_t)v.w;
        }
        __syncthreads();
        bf16x8 af[4], bfr[4];
#pragma unroll
        for (int i = 0; i < 4; ++i) {
            af[i]  = *(const bf16x8*)&As[wr + i * 16 + lr][lk8];
            bfr[i] = *(const bf16x8*)&Bs[wc + i * 16 + lr][lk8];
        }
#pragma unroll
        for (int mi = 0; mi < 4; ++mi)
#pragma unroll
            for (int ni = 0; ni < 4; ++ni)
                acc[mi][ni] = mfma16(af[mi], bfr[ni], acc[mi][ni]);
    }

#pragma unroll
    for (int mi = 0; mi < 4; ++mi) {
#pragma unroll
        for (int ni = 0; ni < 4; ++ni) {
#pragma unroll
            for (int r = 0; r < 4; ++r) {
                const int row = bm0 + wr + mi * 16 + (lane >> 4) * 4 + r;
                const int col = bn0 + wc + ni * 16 + (lane & 15);
                const float val = acc[mi][ni][r] + bias[col];
                if (HEADOUT) {
                    const int b = row >> lshift, l = row & ((1 << lshift) - 1);
                    const int h = col >> 6, d = col & 63;
                    outH[(((size_t)(b * H_ + h) << lshift) + l) * DK_ + d] = (bf16_t)val;
                } else {
                    const size_t idx = (size_t)row * N + col;
                    outF[idx] = val + resid[idx];
                }
            }
        }
    }
}

// ---------------------------------------------------------------------------
// Transpose (bh, L, 64) -> (bh, 64, L) bf16, 64x64 LDS tiles.
// ---------------------------------------------------------------------------
__global__ __launch_bounds__(256) void transpose_v_kernel(
    const bf16_t* __restrict__ V, bf16_t* __restrict__ Vt, int L)
{
    __shared__ bf16_t T[64][72];
    const int bh = blockIdx.y, l0 = blockIdx.x * 64;
    const bf16_t* Vb = V + (size_t)bh * L * 64;
    bf16_t* Vtb = Vt + (size_t)bh * 64 * L;
    const int t = threadIdx.x;
    {
        const int lr = t >> 2, dc = (t & 3) * 16;
        const bf16x8 a = *(const bf16x8*)&Vb[(size_t)(l0 + lr) * 64 + dc];
        const bf16x8 b = *(const bf16x8*)&Vb[(size_t)(l0 + lr) * 64 + dc + 8];
#pragma unroll
        for (int j = 0; j < 8; ++j) { T[lr][dc + j] = a[j]; T[lr][dc + 8 + j] = b[j]; }
    }
    __syncthreads();
    {
        const int dr = t >> 2, lc = (t & 3) * 16;
        bf16x8 o0, o1;
#pragma unroll
        for (int j = 0; j < 8; ++j) { o0[j] = T[lc + j][dr]; o1[j] = T[lc + 8 + j][dr]; }
        *(bf16x8*)&Vtb[(size_t)dr * L + l0 + lc]     = o0;
        *(bf16x8*)&Vtb[(size_t)dr * L + l0 + lc + 8] = o1;
    }
}

// ---------------------------------------------------------------------------
// Fused attention: per (bh, 32-q-row tile): QK^T -> LDS(bf16, swizzled),
// softmax (mask applied here, coalesced) -> probs to d_out + LDS, PV from LDS.
// Both branches accumulate into the same O regs.
// ---------------------------------------------------------------------------
template<int LKX>
__device__ inline void scores_phase(bf16_t* Ssh, const bf16_t* Kb,
                                    const bf16x8 qf[2][2], int wave, int lane)
{
    const int lr = lane & 15, lk8 = (lane >> 4) * 8;
    constexpr int STRIP = LKX / 4;
    constexpr int KTS = STRIP / 16;
#pragma unroll
    for (int kt = 0; kt < KTS; ++kt) {
        const int kbase = wave * STRIP + kt * 16;
        f32x4 acc2[2] = {};
#pragma unroll
        for (int ks = 0; ks < 2; ++ks) {
            const bf16x8 bb = *(const bf16x8*)&Kb[(size_t)(kbase + lr) * DK_ + ks * 32 + lk8];
            acc2[0] = mfma16(qf[0][ks], bb, acc2[0]);
            acc2[1] = mfma16(qf[1][ks], bb, acc2[1]);
        }
#pragma unroll
        for (int m = 0; m < 2; ++m)
#pragma unroll
            for (int r = 0; r < 4; ++r) {
                const int row = m * 16 + (lane >> 4) * 4 + r;
                const int col = kbase + (lane & 15);
                Ssh[sidx(row, col)] = (bf16_t)(acc2[m][r] * 0.125f);
            }
    }
}

template<int LKX>
__device__ inline void softmax_phase(bf16_t* Ssh, const void* mask, unsigned flag,
                                     float* Sout, int b, int q0, int wave, int lane)
{
    constexpr int NP = LKX / 256;   // float4 passes per lane
#pragma unroll 1
    for (int i = 0; i < 8; ++i) {
        const int row = wave * 8 + i;
        const int rowg = q0 + row;
        float p[NP * 4];
        float m = -INFINITY;
#pragma unroll
        for (int ps = 0; ps < NP; ++ps) {
            const int col = ps * 256 + lane * 4;
            const bf16x4 sv = *(const bf16x4*)&Ssh[sidx(row, col)];
            const size_t mi = ((size_t)b * LQ_ + rowg) * LKX + col;
            int msk[4];
            if (flag == 0u) {
                const int4 mm = *(const int4*)((const int*)mask + mi);
                msk[0] = mm.x; msk[1] = mm.y; msk[2] = mm.z; msk[3] = mm.w;
            } else if (flag == 2u) {
                const float4 mm = *(const float4*)((const float*)mask + mi);
                msk[0] = (mm.x != 0.f); msk[1] = (mm.y != 0.f);
                msk[2] = (mm.z != 0.f); msk[3] = (mm.w != 0.f);
            } else {
                const uchar4 mm = *(const uchar4*)((const unsigned char*)mask + mi);
                msk[0] = mm.x; msk[1] = mm.y; msk[2] = mm.z; msk[3] = mm.w;
            }
#pragma unroll
            for (int j = 0; j < 4; ++j) {
                const float v = msk[j] ? NEG_ : (float)sv[j];
                p[ps * 4 + j] = v;
                m = fmaxf(m, v);
            }
        }
        m = waveMax(m);
        float s = 0.f;
#pragma unroll
        for (int j = 0; j < NP * 4; ++j) { p[j] = __expf(p[j] - m); s += p[j]; }
        s = waveSum(s);
        const float inv = 1.f / s;
#pragma unroll
        for (int ps = 0; ps < NP; ++ps) {
            const int col = ps * 256 + lane * 4;
            f32x4 o; bf16x4 pb;
#pragma unroll
            for (int j = 0; j < 4; ++j) {
                const float v = p[ps * 4 + j] * inv;
                o[j] = v; pb[j] = (bf16_t)v;
            }
            __builtin_nontemporal_store(o, (f32x4*)&Sout[(size_t)rowg * LKX + col]);
            *(bf16x4*)&Ssh[sidx(row, col)] = pb;
        }
    }
}

template<int LKX>
__device__ inline void pv_phase(const bf16_t* Ssh, const bf16_t* Vtb,
                                f32x4 acc_o[2], int wave, int lane)
{
    const int lr = lane & 15, lk8 = (lane >> 4) * 8;
    const int d0 = wave * 16;
#pragma unroll
    for (int ks = 0; ks < LKX / 32; ++ks) {
        const bf16x8 bb = *(const bf16x8*)&Vtb[(size_t)(d0 + lr) * LKX + ks * 32 + lk8];
#pragma unroll
        for (int m = 0; m < 2; ++m) {
            const bf16x8 a = *(const bf16x8*)&Ssh[sidx(m * 16 + lr, ks * 32 + lk8)];
            acc_o[m] = mfma16(a, bb, acc_o[m]);
        }
    }
}

__global__ __launch_bounds__(256) void fused_attn_kernel(
    const bf16_t* __restrict__ Qh, const bf16_t* __restrict__ Kh,
    const bf16_t* __restrict__ Klh,
    const bf16_t* __restrict__ Vt, const bf16_t* __restrict__ Vlt,
    const void* __restrict__ mask, const void* __restrict__ maskl,
    const unsigned* __restrict__ flagp,
    float* __restrict__ Sc, float* __restrict__ Sl, float* __restrict__ comb)
{
    __shared__ bf16_t Ssh[32 * 1024];   // exactly 64 KB
    const int bh = blockIdx.y, b = bh >> 4, h = bh & 15;
    const int q0 = blockIdx.x * 32;
    const int wave = threadIdx.x >> 6, lane = threadIdx.x & 63;
    const int lr = lane & 15, lk8 = (lane >> 4) * 8;
    const unsigned flag = *flagp;

    // Q fragments, reused for both branches
    const bf16_t* Qb = Qh + (size_t)bh * LQ_ * DK_;
    bf16x8 qf[2][2];
#pragma unroll
    for (int m = 0; m < 2; ++m)
#pragma unroll
        for (int ks = 0; ks < 2; ++ks)
            qf[m][ks] = *(const bf16x8*)&Qb[(size_t)(q0 + m * 16 + lr) * DK_ + ks * 32 + lk8];

    f32x4 acc_o[2] = {};

    // ---- branch c ----
    scores_phase<LK_>(Ssh, Kh + (size_t)bh * LK_ * DK_, qf, wave, lane);
    __syncthreads();
    softmax_phase<LK_>(Ssh, mask, flag, Sc + (size_t)bh * LQ_ * LK_, b, q0, wave, lane);
    __syncthreads();
    pv_phase<LK_>(Ssh, Vt + (size_t)bh * DK_ * LK_, acc_o, wave, lane);
    __syncthreads();

    // ---- branch l ----
    scores_phase<LKL_>(Ssh, Klh + (size_t)bh * LKL_ * DK_, qf, wave, lane);
    __syncthreads();
    softmax_phase<LKL_>(Ssh, maskl, flag, Sl + (size_t)bh * LQ_ * LKL_, b, q0, wave, lane);
    __syncthreads();
    pv_phase<LKL_>(Ssh, Vlt + (size_t)bh * DK_ * LKL_, acc_o, wave, lane);

    // ---- epilogue: comb = 0.5*(Oc + Ol) ----
    const int d0 = wave * 16;
#pragma unroll
    for (int m = 0; m < 2; ++m)
#pragma unroll
        for (int r = 0; r < 4; ++r) {
            const int row = q0 + m * 16 + (lane >> 4) * 4 + r;
            comb[((size_t)b * LQ_ + row) * HDK_ + h * DK_ + d0 + (lane & 15)] = 0.5f * acc_o[m][r];
        }
}

// ---------------------------------------------------------------------------
// LayerNorm over last dim (1024).
// ---------------------------------------------------------------------------
__global__ __launch_bounds__(256) void ln_kernel(
    const float* __restrict__ Y, const float* __restrict__ g,
    const float* __restrict__ be, float* __restrict__ out)
{
    __shared__ float red1[4], red2[4];
    const int tid = threadIdx.x, wave = tid >> 6, lane = tid & 63;
    const float* p = Y + (size_t)blockIdx.x * DX_;
    const float4 x = *(const float4*)&p[tid * 4];
    float s  = x.x + x.y + x.z + x.w;
    float ss = x.x * x.x + x.y * x.y + x.z * x.z + x.w * x.w;
    s = waveSum(s); ss = waveSum(ss);
    if (lane == 0) { red1[wave] = s; red2[wave] = ss; }
    __syncthreads();
    s  = red1[0] + red1[1] + red1[2] + red1[3];
    ss = red2[0] + red2[1] + red2[2] + red2[3];
    const float mean = s * (1.f / DX_);
    const float var  = ss * (1.f / DX_) - mean * mean;
    const float rstd = rsqrtf(var + EPS_);
    const float4 gg = *(const float4*)&g[tid * 4];
    const float4 bb = *(const float4*)&be[tid * 4];
    float4 o;
    o.x = (x.x - mean) * rstd * gg.x + bb.x;
    o.y = (x.y - mean) * rstd * gg.y + bb.y;
    o.z = (x.z - mean) * rstd * gg.z + bb.z;
    o.w = (x.w - mean) * rstd * gg.w + bb.w;
    *(float4*)&out[(size_t)blockIdx.x * DX_ + tid * 4] = o;
}

// ---------------------------------------------------------------------------
extern "C" void kernel_launch(void* const* d_in, const int* in_sizes, int n_in,
                              void* d_out, int out_size, void* d_ws, size_t ws_size,
                              hipStream_t stream)
{
    const float* q    = (const float*)d_in[0];
    const float* k    = (const float*)d_in[1];
    const float* v    = (const float*)d_in[2];
    const float* kl   = (const float*)d_in[3];
    const float* vl   = (const float*)d_in[4];
    const void*  mask  = d_in[5];
    const void*  maskl = d_in[6];
    const float* wq_w  = (const float*)d_in[7];
    const float* wq_b  = (const float*)d_in[8];
    const float* wk_w  = (const float*)d_in[9];
    const float* wk_b  = (const float*)d_in[10];
    const float* wv_w  = (const float*)d_in[11];
    const float* wv_b  = (const float*)d_in[12];
    const float* wkl_w = (const float*)d_in[13];
    const float* wkl_b = (const float*)d_in[14];
    const float* wvl_w = (const float*)d_in[15];
    const float* wvl_b = (const float*)d_in[16];
    const float* wo_w  = (const float*)d_in[17];
    const float* wo_b  = (const float*)d_in[18];
    const float* ln_g  = (const float*)d_in[19];
    const float* ln_b  = (const float*)d_in[20];

    char* ws = (char*)d_ws;
    const size_t MiB = 1u << 20;
    bf16_t* qh   = (bf16_t*)(ws);                 //  0..8
    bf16_t* kh   = (bf16_t*)(ws +  8 * MiB);      //  8..16
    bf16_t* klh  = (bf16_t*)(ws + 16 * MiB);      // 16..20
    bf16_t* vh   = (bf16_t*)(ws + 20 * MiB);      // 20..28
    bf16_t* vlh  = (bf16_t*)(ws + 28 * MiB);      // 28..32
    bf16_t* vt   = (bf16_t*)(ws + 32 * MiB);      // 32..40
    bf16_t* vlt  = (bf16_t*)(ws + 40 * MiB);      // 40..44
    unsigned* flag = (unsigned*)(ws + 44 * MiB);  // 44
    float*  comb = (float*) (ws + 48 * MiB);      // 48..64
    float*  ypre = (float*) (ws);                 // reuse 0..16 (qh/kh dead by then)

    float* y_out = (float*)d_out;
    float* Sc = y_out + (size_t)B_ * LQ_ * DX_;
    float* Sl = Sc + (size_t)B_ * H_ * LQ_ * LK_;

    detect_mask_kernel<<<dim3(1), dim3(256), 0, stream>>>((const unsigned*)mask, flag);

    // Projections -> bf16 head tensors (B,H,L,DK)
    gemm_bf16_kernel<true><<<dim3(8, 32), 256, 0, stream>>>(q,  wq_w,  wq_b,  qh,  nullptr, nullptr, 4096, 1024, 1024, 10);
    gemm_bf16_kernel<true><<<dim3(8, 32), 256, 0, stream>>>(k,  wk_w,  wk_b,  kh,  nullptr, nullptr, 4096, 1024, 1024, 10);
    gemm_bf16_kernel<true><<<dim3(8, 32), 256, 0, stream>>>(v,  wv_w,  wv_b,  vh,  nullptr, nullptr, 4096, 1024, 1024, 10);
    gemm_bf16_kernel<true><<<dim3(8, 16), 256, 0, stream>>>(kl, wkl_w, wkl_b, klh, nullptr, nullptr, 2048, 1024, 1024,  9);
    gemm_bf16_kernel<true><<<dim3(8, 16), 256, 0, stream>>>(vl, wvl_w, wvl_b, vlh, nullptr, nullptr, 2048, 1024, 1024,  9);

    // V head tensors -> transposed (B,H,DK,L) for contiguous PV B-fragments
    transpose_v_kernel<<<dim3(16, 64), 256, 0, stream>>>(vh,  vt,  LK_);
    transpose_v_kernel<<<dim3( 8, 64), 256, 0, stream>>>(vlh, vlt, LKL_);

    // Fused scores+softmax+PV (writes attn_c/attn_l + comb)
    fused_attn_kernel<<<dim3(32, 64), 256, 0, stream>>>(qh, kh, klh, vt, vlt,
                                                        mask, maskl, flag, Sc, Sl, comb);

    // Output projection + bias + residual(q) -> ypre
    gemm_bf16_kernel<false><<<dim3(8, 32), 256, 0, stream>>>(comb, wo_w, wo_b, nullptr, ypre, q, 4096, 1024, 1024, 0);

    // LayerNorm -> y
    ln_kernel<<<4096, 256, 0, stream>>>(ypre, ln_g, ln_b, y_out);
}

// Round 3
// 579.763 us; speedup vs baseline: 1.5970x; 1.1046x over previous
//
#include <hip/hip_runtime.h>
#include <hip/hip_bf16.h>

#define B_   4
#define LQ_  1024
#define LK_  1024
#define LKL_ 512
#define DX_  1024
#define H_   16
#define DK_  64
#define HDK_ 1024
#define NEG_ -1e9f
#define EPS_ 1e-5f

typedef __bf16 bf16_t;
typedef __bf16 bf16x8 __attribute__((ext_vector_type(8)));
typedef __bf16 bf16x4 __attribute__((ext_vector_type(4)));
typedef float  f32x4  __attribute__((ext_vector_type(4)));

__device__ inline f32x4 mfma16(bf16x8 a, bf16x8 b, f32x4 c) {
    return __builtin_amdgcn_mfma_f32_16x16x32_bf16(a, b, c, 0, 0, 0);
}

__device__ inline float waveMax(float v) {
#pragma unroll
    for (int o = 32; o > 0; o >>= 1) v = fmaxf(v, __shfl_xor(v, o, 64));
    return v;
}
__device__ inline float waveSum(float v) {
#pragma unroll
    for (int o = 32; o > 0; o >>= 1) v += __shfl_xor(v, o, 64);
    return v;
}

// XOR-swizzle: spread a column-slice read (16 rows, same col) across banks.
// STRIDE in elements; swizzle moves 8-element (16B) slots via row bits.
template<int STRIDE>
__device__ inline int sidx(int row, int col) {
    return (row * STRIDE + col) ^ ((row & 15) << 3);
}

// ---------------------------------------------------------------------------
// Detect mask materialization: int32 (0), uint8 (1), float32 (2).
// ---------------------------------------------------------------------------
__global__ void detect_mask_kernel(const unsigned* __restrict__ m, unsigned* __restrict__ flag)
{
    __shared__ unsigned w[256];
    w[threadIdx.x] = m[threadIdx.x];
    __syncthreads();
    if (threadIdx.x == 0) {
        bool all01 = true, allf = true;
        for (int i = 0; i < 256; ++i) {
            unsigned v = w[i];
            all01 = all01 && (v <= 1u);
            allf  = allf  && (v == 0u || v == 0x3F800000u);
        }
        *flag = all01 ? 0u : (allf ? 2u : 1u);
    }
}

// ---------------------------------------------------------------------------
// Bit-pack both masks: 25 MB int32/u8/f32 -> 768 KB of bits (1 = masked).
// One wave covers 64 consecutive elements -> one u64 via ballot.
// ---------------------------------------------------------------------------
__global__ __launch_bounds__(256) void bitpack_mask_kernel(
    const void* __restrict__ mc, const void* __restrict__ ml,
    const unsigned* __restrict__ flagp,
    unsigned long long* __restrict__ bc, unsigned long long* __restrict__ bl)
{
    const unsigned flag = *flagp;
    const size_t NC = (size_t)B_ * LQ_ * LK_;      // 4194304 (div by 256)
    const int lane = threadIdx.x & 63;
    const size_t g = (size_t)blockIdx.x * 256 + threadIdx.x;
    const bool inC = g < NC;
    const size_t idx = inC ? g : g - NC;
    const void* src = inC ? mc : ml;
    bool m;
    if (flag == 0u)      m = ((const int*)src)[idx] != 0;
    else if (flag == 2u) m = ((const float*)src)[idx] != 0.0f;
    else                 m = ((const unsigned char*)src)[idx] != 0;
    const unsigned long long bal = __ballot(m);
    if (lane == 0) {
        unsigned long long* dst = inC ? bc : bl;
        dst[idx >> 6] = bal;
    }
}

// ---------------------------------------------------------------------------
// Projection GEMM: C = A(f32,MxK) * W(f32,KxN) + bias.
// HEADOUT: bf16 (B,H,L,DK).  else: f32 + residual.
// ---------------------------------------------------------------------------
template<bool HEADOUT>
__global__ __launch_bounds__(256) void gemm_bf16_kernel(
    const float* __restrict__ A, const float* __restrict__ W,
    const float* __restrict__ bias,
    bf16_t* __restrict__ outH, float* __restrict__ outF,
    const float* __restrict__ resid,
    int M, int N, int K, int lshift)
{
    __shared__ bf16_t As[128][40];
    __shared__ bf16_t Bs[128][40];
    const int tid  = threadIdx.x;
    const int wave = tid >> 6, lane = tid & 63;
    const int bm0 = blockIdx.y * 128, bn0 = blockIdx.x * 128;
    const int wr = (wave >> 1) * 64, wc = (wave & 1) * 64;
    const int lr = lane & 15, lk8 = (lane >> 4) * 8;

    f32x4 acc[4][4] = {};

    const int fA = (tid & 7) * 4;
    const int rA = tid >> 3;
    const int fB = (tid & 31) * 4;
    const int kB = tid >> 5;

    for (int k0 = 0; k0 < K; k0 += 32) {
        __syncthreads();
#pragma unroll
        for (int rr = 0; rr < 4; ++rr) {
            const int r = rA + rr * 32;
            const float4 v = *(const float4*)&A[(size_t)(bm0 + r) * K + k0 + fA];
            bf16x4 t;
            t[0] = (bf16_t)v.x; t[1] = (bf16_t)v.y; t[2] = (bf16_t)v.z; t[3] = (bf16_t)v.w;
            *(bf16x4*)&As[r][fA] = t;
        }
#pragma unroll
        for (int kk = 0; kk < 4; ++kk) {
            const int kx = kB + kk * 8;
            const float4 v = *(const float4*)&W[(size_t)(k0 + kx) * N + bn0 + fB];
            Bs[fB + 0][kx] = (bf16_t)v.x;
            Bs[fB + 1][kx] = (bf16_t)v.y;
            Bs[fB + 2][kx] = (bf16_t)v.z;
            Bs[fB + 3][kx] = (bf16_t)v.w;
        }
        __syncthreads();
        bf16x8 af[4], bfr[4];
#pragma unroll
        for (int i = 0; i < 4; ++i) {
            af[i]  = *(const bf16x8*)&As[wr + i * 16 + lr][lk8];
            bfr[i] = *(const bf16x8*)&Bs[wc + i * 16 + lr][lk8];
        }
#pragma unroll
        for (int mi = 0; mi < 4; ++mi)
#pragma unroll
            for (int ni = 0; ni < 4; ++ni)
                acc[mi][ni] = mfma16(af[mi], bfr[ni], acc[mi][ni]);
    }

#pragma unroll
    for (int mi = 0; mi < 4; ++mi) {
#pragma unroll
        for (int ni = 0; ni < 4; ++ni) {
#pragma unroll
            for (int r = 0; r < 4; ++r) {
                const int row = bm0 + wr + mi * 16 + (lane >> 4) * 4 + r;
                const int col = bn0 + wc + ni * 16 + (lane & 15);
                const float val = acc[mi][ni][r] + bias[col];
                if (HEADOUT) {
                    const int b = row >> lshift, l = row & ((1 << lshift) - 1);
                    const int h = col >> 6, d = col & 63;
                    outH[(((size_t)(b * H_ + h) << lshift) + l) * DK_ + d] = (bf16_t)val;
                } else {
                    const size_t idx = (size_t)row * N + col;
                    outF[idx] = val + resid[idx];
                }
            }
        }
    }
}

// ---------------------------------------------------------------------------
// Transpose (bh, L, 64) -> (bh, 64, L) bf16.
// ---------------------------------------------------------------------------
__global__ __launch_bounds__(256) void transpose_v_kernel(
    const bf16_t* __restrict__ V, bf16_t* __restrict__ Vt, int L)
{
    __shared__ bf16_t T[64][72];
    const int bh = blockIdx.y, l0 = blockIdx.x * 64;
    const bf16_t* Vb = V + (size_t)bh * L * 64;
    bf16_t* Vtb = Vt + (size_t)bh * 64 * L;
    const int t = threadIdx.x;
    {
        const int lr = t >> 2, dc = (t & 3) * 16;
        const bf16x8 a = *(const bf16x8*)&Vb[(size_t)(l0 + lr) * 64 + dc];
        const bf16x8 b = *(const bf16x8*)&Vb[(size_t)(l0 + lr) * 64 + dc + 8];
#pragma unroll
        for (int j = 0; j < 8; ++j) { T[lr][dc + j] = a[j]; T[lr][dc + 8 + j] = b[j]; }
    }
    __syncthreads();
    {
        const int dr = t >> 2, lc = (t & 3) * 16;
        bf16x8 o0, o1;
#pragma unroll
        for (int j = 0; j < 8; ++j) { o0[j] = T[lc + j][dr]; o1[j] = T[lc + 8 + j][dr]; }
        *(bf16x8*)&Vtb[(size_t)dr * L + l0 + lc]     = o0;
        *(bf16x8*)&Vtb[(size_t)dr * L + l0 + lc + 8] = o1;
    }
}

// ---------------------------------------------------------------------------
// Fused attention, 16 q-rows per block, both branches, 2 barriers total.
// ---------------------------------------------------------------------------
template<int LKX>
__device__ inline void scores16(bf16_t* __restrict__ Ssh, const bf16_t* __restrict__ Kb,
                                const bf16x8 qf[2], int wave, int lane)
{
    const int lr = lane & 15, lk8 = (lane >> 4) * 8;
    constexpr int KTS = LKX / 64;   // 16-col tiles per wave strip
#pragma unroll
    for (int kt = 0; kt < KTS; ++kt) {
        const int kbase = wave * (LKX / 4) + kt * 16;
        f32x4 acc = {};
#pragma unroll
        for (int ks = 0; ks < 2; ++ks) {
            const bf16x8 bb = *(const bf16x8*)&Kb[(size_t)(kbase + lr) * DK_ + ks * 32 + lk8];
            acc = mfma16(qf[ks], bb, acc);
        }
#pragma unroll
        for (int r = 0; r < 4; ++r) {
            const int row = (lane >> 4) * 4 + r;
            const int col = kbase + (lane & 15);
            Ssh[sidx<LKX>(row, col)] = (bf16_t)(acc[r] * 0.125f);
        }
    }
}

template<int LKX>
__device__ inline void softmax16(bf16_t* __restrict__ Ssh, const unsigned* __restrict__ bits,
                                 float* __restrict__ Sout, int b, int q0, int wave, int lane)
{
    constexpr int NP = LKX / 256;
#pragma unroll 1
    for (int i = 0; i < 4; ++i) {
        const int row = wave * 4 + i;
        const int rowg = q0 + row;
        const size_t rowbase = ((size_t)b * LQ_ + rowg) * LKX;
        float p[NP * 4];
        float m = -INFINITY;
#pragma unroll
        for (int ps = 0; ps < NP; ++ps) {
            const int col = ps * 256 + lane * 4;
            const bf16x4 sv = *(const bf16x4*)&Ssh[sidx<LKX>(row, col)];
            const unsigned word = bits[(rowbase + col) >> 5];
            const unsigned mb = word >> (col & 31);
#pragma unroll
            for (int j = 0; j < 4; ++j) {
                const float v = ((mb >> j) & 1u) ? NEG_ : (float)sv[j];
                p[ps * 4 + j] = v;
                m = fmaxf(m, v);
            }
        }
        m = waveMax(m);
        float s = 0.f;
#pragma unroll
        for (int j = 0; j < NP * 4; ++j) { p[j] = __expf(p[j] - m); s += p[j]; }
        s = waveSum(s);
        const float inv = 1.f / s;
#pragma unroll
        for (int ps = 0; ps < NP; ++ps) {
            const int col = ps * 256 + lane * 4;
            f32x4 o; bf16x4 pb;
#pragma unroll
            for (int j = 0; j < 4; ++j) {
                const float v = p[ps * 4 + j] * inv;
                o[j] = v; pb[j] = (bf16_t)v;
            }
            __builtin_nontemporal_store(o, (f32x4*)&Sout[(size_t)rowg * LKX + col]);
            *(bf16x4*)&Ssh[sidx<LKX>(row, col)] = pb;
        }
    }
}

template<int LKX>
__device__ inline void pv16(const bf16_t* __restrict__ Ssh, const bf16_t* __restrict__ Vtb,
                            f32x4& acc_o, int wave, int lane)
{
    const int lr = lane & 15, lk8 = (lane >> 4) * 8;
    const int d0 = wave * 16;
#pragma unroll
    for (int ks = 0; ks < LKX / 32; ++ks) {
        const bf16x8 bb = *(const bf16x8*)&Vtb[(size_t)(d0 + lr) * LKX + ks * 32 + lk8];
        const bf16x8 a  = *(const bf16x8*)&Ssh[sidx<LKX>(lr, ks * 32 + lk8)];
        acc_o = mfma16(a, bb, acc_o);
    }
}

__global__ __launch_bounds__(256, 3) void fused_attn_kernel(
    const bf16_t* __restrict__ Qh, const bf16_t* __restrict__ Kh,
    const bf16_t* __restrict__ Klh,
    const bf16_t* __restrict__ Vt, const bf16_t* __restrict__ Vlt,
    const unsigned* __restrict__ bitc, const unsigned* __restrict__ bitl,
    float* __restrict__ Sc, float* __restrict__ Sl, float* __restrict__ comb)
{
    __shared__ bf16_t Sshc[16 * 1024];   // 32 KB
    __shared__ bf16_t Sshl[16 * 512];    // 16 KB
    // XCD-bijective swizzle: 4096 blocks, 512 per XCD, 8 bh per XCD.
    const int sid = (blockIdx.x & 7) * 512 + (blockIdx.x >> 3);
    const int bh = sid >> 6, qt = sid & 63;
    const int b = bh >> 4, h = bh & 15;
    const int q0 = qt * 16;
    const int wave = threadIdx.x >> 6, lane = threadIdx.x & 63;
    const int lr = lane & 15, lk8 = (lane >> 4) * 8;

    // Q fragments (16 rows), reused for both branches
    const bf16_t* Qb = Qh + (size_t)bh * LQ_ * DK_;
    bf16x8 qf[2];
#pragma unroll
    for (int ks = 0; ks < 2; ++ks)
        qf[ks] = *(const bf16x8*)&Qb[(size_t)(q0 + lr) * DK_ + ks * 32 + lk8];

    scores16<LK_ >(Sshc, Kh  + (size_t)bh * LK_  * DK_, qf, wave, lane);
    scores16<LKL_>(Sshl, Klh + (size_t)bh * LKL_ * DK_, qf, wave, lane);
    __syncthreads();
    softmax16<LK_ >(Sshc, bitc, Sc + (size_t)bh * LQ_ * LK_,  b, q0, wave, lane);
    softmax16<LKL_>(Sshl, bitl, Sl + (size_t)bh * LQ_ * LKL_, b, q0, wave, lane);
    __syncthreads();
    f32x4 acc_o = {};
    pv16<LK_ >(Sshc, Vt  + (size_t)bh * DK_ * LK_,  acc_o, wave, lane);
    pv16<LKL_>(Sshl, Vlt + (size_t)bh * DK_ * LKL_, acc_o, wave, lane);

    const int d0 = wave * 16;
#pragma unroll
    for (int r = 0; r < 4; ++r) {
        const int row = q0 + (lane >> 4) * 4 + r;
        comb[((size_t)b * LQ_ + row) * HDK_ + h * DK_ + d0 + (lane & 15)] = 0.5f * acc_o[r];
    }
}

// ---------------------------------------------------------------------------
// LayerNorm over last dim (1024).
// ---------------------------------------------------------------------------
__global__ __launch_bounds__(256) void ln_kernel(
    const float* __restrict__ Y, const float* __restrict__ g,
    const float* __restrict__ be, float* __restrict__ out)
{
    __shared__ float red1[4], red2[4];
    const int tid = threadIdx.x, wave = tid >> 6, lane = tid & 63;
    const float* p = Y + (size_t)blockIdx.x * DX_;
    const float4 x = *(const float4*)&p[tid * 4];
    float s  = x.x + x.y + x.z + x.w;
    float ss = x.x * x.x + x.y * x.y + x.z * x.z + x.w * x.w;
    s = waveSum(s); ss = waveSum(ss);
    if (lane == 0) { red1[wave] = s; red2[wave] = ss; }
    __syncthreads();
    s  = red1[0] + red1[1] + red1[2] + red1[3];
    ss = red2[0] + red2[1] + red2[2] + red2[3];
    const float mean = s * (1.f / DX_);
    const float var  = ss * (1.f / DX_) - mean * mean;
    const float rstd = rsqrtf(var + EPS_);
    const float4 gg = *(const float4*)&g[tid * 4];
    const float4 bb = *(const float4*)&be[tid * 4];
    float4 o;
    o.x = (x.x - mean) * rstd * gg.x + bb.x;
    o.y = (x.y - mean) * rstd * gg.y + bb.y;
    o.z = (x.z - mean) * rstd * gg.z + bb.z;
    o.w = (x.w - mean) * rstd * gg.w + bb.w;
    *(float4*)&out[(size_t)blockIdx.x * DX_ + tid * 4] = o;
}

// ---------------------------------------------------------------------------
extern "C" void kernel_launch(void* const* d_in, const int* in_sizes, int n_in,
                              void* d_out, int out_size, void* d_ws, size_t ws_size,
                              hipStream_t stream)
{
    const float* q    = (const float*)d_in[0];
    const float* k    = (const float*)d_in[1];
    const float* v    = (const float*)d_in[2];
    const float* kl   = (const float*)d_in[3];
    const float* vl   = (const float*)d_in[4];
    const void*  mask  = d_in[5];
    const void*  maskl = d_in[6];
    const float* wq_w  = (const float*)d_in[7];
    const float* wq_b  = (const float*)d_in[8];
    const float* wk_w  = (const float*)d_in[9];
    const float* wk_b  = (const float*)d_in[10];
    const float* wv_w  = (const float*)d_in[11];
    const float* wv_b  = (const float*)d_in[12];
    const float* wkl_w = (const float*)d_in[13];
    const float* wkl_b = (const float*)d_in[14];
    const float* wvl_w = (const float*)d_in[15];
    const float* wvl_b = (const float*)d_in[16];
    const float* wo_w  = (const float*)d_in[17];
    const float* wo_b  = (const float*)d_in[18];
    const float* ln_g  = (const float*)d_in[19];
    const float* ln_b  = (const float*)d_in[20];

    char* ws = (char*)d_ws;
    const size_t MiB = 1u << 20;
    bf16_t* qh   = (bf16_t*)(ws);                 //  0..8
    bf16_t* kh   = (bf16_t*)(ws +  8 * MiB);      //  8..16
    bf16_t* klh  = (bf16_t*)(ws + 16 * MiB);      // 16..20
    bf16_t* vh   = (bf16_t*)(ws + 20 * MiB);      // 20..28
    bf16_t* vlh  = (bf16_t*)(ws + 28 * MiB);      // 28..32
    bf16_t* vt   = (bf16_t*)(ws + 32 * MiB);      // 32..40
    bf16_t* vlt  = (bf16_t*)(ws + 40 * MiB);      // 40..44
    unsigned* flag = (unsigned*)(ws + 44 * MiB);  // 44
    unsigned long long* bitc = (unsigned long long*)(ws + 45 * MiB);            // 512 KB
    unsigned long long* bitl = (unsigned long long*)(ws + 45 * MiB + 512 * 1024); // 256 KB
    float*  comb = (float*) (ws + 48 * MiB);      // 48..64
    float*  ypre = (float*) (ws);                 // reuse 0..16 (qh/kh dead)

    float* y_out = (float*)d_out;
    float* Sc = y_out + (size_t)B_ * LQ_ * DX_;
    float* Sl = Sc + (size_t)B_ * H_ * LQ_ * LK_;

    detect_mask_kernel<<<dim3(1), dim3(256), 0, stream>>>((const unsigned*)mask, flag);
    bitpack_mask_kernel<<<dim3((B_*LQ_*(LK_+LKL_)) / 256), 256, 0, stream>>>(
        mask, maskl, flag, bitc, bitl);

    // Projections -> bf16 head tensors (B,H,L,DK)
    gemm_bf16_kernel<true><<<dim3(8, 32), 256, 0, stream>>>(q,  wq_w,  wq_b,  qh,  nullptr, nullptr, 4096, 1024, 1024, 10);
    gemm_bf16_kernel<true><<<dim3(8, 32), 256, 0, stream>>>(k,  wk_w,  wk_b,  kh,  nullptr, nullptr, 4096, 1024, 1024, 10);
    gemm_bf16_kernel<true><<<dim3(8, 32), 256, 0, stream>>>(v,  wv_w,  wv_b,  vh,  nullptr, nullptr, 4096, 1024, 1024, 10);
    gemm_bf16_kernel<true><<<dim3(8, 16), 256, 0, stream>>>(kl, wkl_w, wkl_b, klh, nullptr, nullptr, 2048, 1024, 1024,  9);
    gemm_bf16_kernel<true><<<dim3(8, 16), 256, 0, stream>>>(vl, wvl_w, wvl_b, vlh, nullptr, nullptr, 2048, 1024, 1024,  9);

    // V head tensors -> transposed (B,H,DK,L)
    transpose_v_kernel<<<dim3(16, 64), 256, 0, stream>>>(vh,  vt,  LK_);
    transpose_v_kernel<<<dim3( 8, 64), 256, 0, stream>>>(vlh, vlt, LKL_);

    // Fused scores+softmax+PV (writes attn_c/attn_l + comb)
    fused_attn_kernel<<<dim3(4096), 256, 0, stream>>>(qh, kh, klh, vt, vlt,
                                                      (const unsigned*)bitc, (const unsigned*)bitl,
                                                      Sc, Sl, comb);

    // Output projection + bias + residual(q) -> ypre
    gemm_bf16_kernel<false><<<dim3(8, 32), 256, 0, stream>>>(comb, wo_w, wo_b, nullptr, ypre, q, 4096, 1024, 1024, 0);

    // LayerNorm -> y
    ln_kernel<<<4096, 256, 0, stream>>>(ypre, ln_g, ln_b, y_out);
}